// Round 6
// baseline (81.314 us; speedup 1.0000x reference)
//
#include <hip/hip_runtime.h>
#include <hip/hip_bf16.h>

// Model dims (fixed by the reference)
#define R_ 64
#define S_ 32
#define T_ 50
#define E_ 512
#define U_ 20
#define D_ 532   // E + U
#define L_ 9
#define NSENT (R_ * S_)   // 2048

#define PCHUNK 128
#define NCG 5   // ceil(532/128) column groups
#define NKG 5   // ceil(532/128) k groups

typedef __attribute__((ext_vector_type(8))) short bf16x8;
typedef __attribute__((ext_vector_type(4))) float f32x4;

__device__ __forceinline__ float selu_f(float x) {
    const float scale = 1.0507009873554805f;
    const float alpha = 1.6732632423543772f;
    return x > 0.0f ? scale * x : scale * alpha * expm1f(x);
}

// Kernel A (fused): blocks [0,2048) = per-sentence masked token-mean -> bf16.
// blocks [2048,2560) = transpose-convert {w_sent, w_rev} fp32 [k][n] -> bf16 wT[z][n][k].
// block 0 also zero-inits the D-stage completion counter.
__global__ __launch_bounds__(256) void k_fused_A(
        const int* __restrict__ inputs,       // [R,S,T]
        const float* __restrict__ emb,        // [V,E]
        const float* __restrict__ w_sent,     // [512,512]
        const float* __restrict__ w_rev,      // [512,512]
        __hip_bfloat16* __restrict__ sent_bf, // out [2048,512] bf16
        __hip_bfloat16* __restrict__ wT,      // out [2][512][512] bf16 (transposed)
        float* __restrict__ smask,            // out [2048]
        int* __restrict__ dcount)             // out: =0
{
    const int tid = threadIdx.x;

    if (blockIdx.x >= NSENT) {
        // ---- weight transpose-convert: 512 blocks of 32x32 tiles ----
        __shared__ float tile[32][33];
        const int b = blockIdx.x - NSENT;                 // 0..511
        const int z = b >> 8;                             // 0: w_sent, 1: w_rev
        const float* w = z ? w_rev : w_sent;
        __hip_bfloat16* o = wT + (size_t)z * E_ * E_;
        const int bb = b & 255;
        const int tx = tid & 31, ty = tid >> 5;           // ty 0..7
        const int k0 = (bb >> 4) * 32, n0 = (bb & 15) * 32;
        #pragma unroll
        for (int i = 0; i < 4; ++i)
            tile[ty + 8 * i][tx] = w[(size_t)(k0 + ty + 8 * i) * E_ + n0 + tx];
        __syncthreads();
        #pragma unroll
        for (int i = 0; i < 4; ++i)
            o[(size_t)(n0 + ty + 8 * i) * E_ + k0 + tx] = __float2bfloat16(tile[tx][ty + 8 * i]);
        return;
    }

    if (blockIdx.x == 0 && tid == 0) *dcount = 0;

    // ---- sentence masked mean (256 threads x float2; unconditional gather) ----
    const int sid = blockIdx.x;
    const int base = sid * T_;
    float2 acc = {0.f, 0.f};
    int cnt = 0;
    for (int t = 0; t < T_; ++t) {
        const int tok = inputs[base + t];     // wave-uniform -> scalar broadcast
        const float m = (tok != 0) ? 1.0f : 0.0f;
        cnt += (tok != 0);
        // unconditional load (tok==0 reads row 0, nullified by m) -> pipelinable
        const float2 v = ((const float2*)(emb + (size_t)tok * E_))[tid];
        acc.x = fmaf(v.x, m, acc.x);
        acc.y = fmaf(v.y, m, acc.y);
    }
    const float inv = 1.0f / fmaxf((float)cnt, 1.0f);
    __hip_bfloat162 h2;
    h2.x = __float2bfloat16(acc.x * inv);
    h2.y = __float2bfloat16(acc.y * inv);
    ((__hip_bfloat162*)(sent_bf + (size_t)sid * E_))[tid] = h2;
    if (tid == 0) smask[sid] = (cnt > 0) ? 1.0f : 0.0f;   // tokens >= 0
}

// Kernel G1: sent GEMM + masked-mean epilogue.
// sent_h = selu(sent_bf @ w_sentT + b_sent) is NOT materialized; instead each
// block reduces its 64-row tile (= 32 sentences x 2 reviews; review == wm)
// into mrev[2*bm+wm][cols of this block], weighted by smask.
// grid = (512/64, 2048/64) = (8,32), block 256.
__global__ __launch_bounds__(256) void k_gemm_sent_mean(
        const __hip_bfloat16* __restrict__ A,   // [2048,512] bf16
        const __hip_bfloat16* __restrict__ Bt,  // [512,512]  Bt[n][k]
        const float* __restrict__ bias,         // [512]
        const float* __restrict__ smask,        // [2048]
        __hip_bfloat16* __restrict__ mrev)      // out [64,512] bf16
{
    __shared__ short As[64][40];
    __shared__ short Bs[64][40];
    const int tid  = threadIdx.x;
    const int wid  = tid >> 6;
    const int lane = tid & 63;
    const int wm = wid >> 1, wn = wid & 1;
    const int bm = blockIdx.y * 64, bn = blockIdx.x * 64;

    const int srow = tid >> 2;
    const int soff = (tid & 3) * 8;

    const short* Ag  = (const short*)A;
    const short* Btg = (const short*)Bt;

    f32x4 acc[2][2];
    #pragma unroll
    for (int i = 0; i < 2; ++i)
        #pragma unroll
        for (int j = 0; j < 2; ++j) acc[i][j] = (f32x4){0.f, 0.f, 0.f, 0.f};

    const int fr = lane & 15;
    const int kg = (lane >> 4) * 8;

    for (int k0 = 0; k0 < E_; k0 += 32) {
        __syncthreads();
        *(bf16x8*)&As[srow][soff] = *(const bf16x8*)&Ag[(size_t)(bm + srow) * E_ + k0 + soff];
        *(bf16x8*)&Bs[srow][soff] = *(const bf16x8*)&Btg[(size_t)(bn + srow) * E_ + k0 + soff];
        __syncthreads();
        bf16x8 af0 = *(const bf16x8*)&As[wm * 32 + fr][kg];
        bf16x8 af1 = *(const bf16x8*)&As[wm * 32 + 16 + fr][kg];
        bf16x8 bf0 = *(const bf16x8*)&Bs[wn * 32 + fr][kg];
        bf16x8 bf1 = *(const bf16x8*)&Bs[wn * 32 + 16 + fr][kg];
        acc[0][0] = __builtin_amdgcn_mfma_f32_16x16x32_bf16(af0, bf0, acc[0][0], 0, 0, 0);
        acc[0][1] = __builtin_amdgcn_mfma_f32_16x16x32_bf16(af0, bf1, acc[0][1], 0, 0, 0);
        acc[1][0] = __builtin_amdgcn_mfma_f32_16x16x32_bf16(af1, bf0, acc[1][0], 0, 0, 0);
        acc[1][1] = __builtin_amdgcn_mfma_f32_16x16x32_bf16(af1, bf1, acc[1][1], 0, 0, 0);
    }

    // masked-mean epilogue. rows of fragment (fm,j): bm + wm*32 + fm*16 + rq + j.
    const int rq = (lane >> 4) * 4;
    float m[2][4];
    float msum = 0.f;
    #pragma unroll
    for (int fm = 0; fm < 2; ++fm)
        #pragma unroll
        for (int j = 0; j < 4; ++j) {
            m[fm][j] = smask[bm + wm * 32 + fm * 16 + rq + j];
            msum += m[fm][j];
        }
    float colsum[2];
    #pragma unroll
    for (int fn = 0; fn < 2; ++fn) {
        const float bv = bias[bn + wn * 32 + fn * 16 + fr];
        float s = 0.f;
        #pragma unroll
        for (int fm = 0; fm < 2; ++fm)
            #pragma unroll
            for (int j = 0; j < 4; ++j)
                s = fmaf(selu_f(acc[fm][fn][j] + bv), m[fm][j], s);
        colsum[fn] = s;
    }
    // reduce across the 4 rq groups (lanes differing in bits 4,5); fr preserved
    #pragma unroll
    for (int fn = 0; fn < 2; ++fn) {
        colsum[fn] += __shfl_xor(colsum[fn], 16, 64);
        colsum[fn] += __shfl_xor(colsum[fn], 32, 64);
    }
    msum += __shfl_xor(msum, 16, 64);
    msum += __shfl_xor(msum, 32, 64);
    const float inv = 1.0f / fmaxf(msum, 1.0f);
    if (lane < 16) {
        const int g = 2 * blockIdx.y + wm;     // review index
        #pragma unroll
        for (int fn = 0; fn < 2; ++fn)
            mrev[(size_t)g * E_ + bn + wn * 32 + fn * 16 + fr] =
                __float2bfloat16(colsum[fn] * inv);
    }
}

// Kernel G2: rev GEMM -> p_batch cols 0..511 (fp32, ldc=532); block bn==0 also
// writes normalized user-feat cols 512..531. grid = (8,1), block 256.
__global__ __launch_bounds__(256) void k_gemm_rev(
        const __hip_bfloat16* __restrict__ A,   // [64,512] bf16 (mrev)
        const __hip_bfloat16* __restrict__ Bt,  // [512,512]  Bt[n][k]
        const float* __restrict__ bias,         // [512]
        const float* __restrict__ user_feats,   // [64,20]
        const float* __restrict__ user_w,       // [20]
        float* __restrict__ p_batch)            // out [64,532]
{
    __shared__ short As[64][40];
    __shared__ short Bs[64][40];
    const int tid  = threadIdx.x;
    const int wid  = tid >> 6;
    const int lane = tid & 63;
    const int wm = wid >> 1, wn = wid & 1;
    const int bn = blockIdx.x * 64;

    // side-work: user-feat columns (independent of GEMM output)
    if (blockIdx.x == 0 && tid < 64) {
        const int r = tid;
        float ss = 0.f;
        #pragma unroll
        for (int j = 0; j < U_; ++j) {
            const float u = user_feats[r * U_ + j];
            ss = fmaf(u, u, ss);
        }
        const float nrm = fmaxf(sqrtf(ss), 1e-12f);
        #pragma unroll
        for (int j = 0; j < U_; ++j)
            p_batch[(size_t)r * D_ + E_ + j] = user_feats[r * U_ + j] / nrm * user_w[j];
    }

    const int srow = tid >> 2;
    const int soff = (tid & 3) * 8;
    const short* Ag  = (const short*)A;
    const short* Btg = (const short*)Bt;

    f32x4 acc[2][2];
    #pragma unroll
    for (int i = 0; i < 2; ++i)
        #pragma unroll
        for (int j = 0; j < 2; ++j) acc[i][j] = (f32x4){0.f, 0.f, 0.f, 0.f};

    const int fr = lane & 15;
    const int kg = (lane >> 4) * 8;

    for (int k0 = 0; k0 < E_; k0 += 32) {
        __syncthreads();
        *(bf16x8*)&As[srow][soff] = *(const bf16x8*)&Ag[(size_t)srow * E_ + k0 + soff];
        *(bf16x8*)&Bs[srow][soff] = *(const bf16x8*)&Btg[(size_t)(bn + srow) * E_ + k0 + soff];
        __syncthreads();
        bf16x8 af0 = *(const bf16x8*)&As[wm * 32 + fr][kg];
        bf16x8 af1 = *(const bf16x8*)&As[wm * 32 + 16 + fr][kg];
        bf16x8 bf0 = *(const bf16x8*)&Bs[wn * 32 + fr][kg];
        bf16x8 bf1 = *(const bf16x8*)&Bs[wn * 32 + 16 + fr][kg];
        acc[0][0] = __builtin_amdgcn_mfma_f32_16x16x32_bf16(af0, bf0, acc[0][0], 0, 0, 0);
        acc[0][1] = __builtin_amdgcn_mfma_f32_16x16x32_bf16(af0, bf1, acc[0][1], 0, 0, 0);
        acc[1][0] = __builtin_amdgcn_mfma_f32_16x16x32_bf16(af1, bf0, acc[1][0], 0, 0, 0);
        acc[1][1] = __builtin_amdgcn_mfma_f32_16x16x32_bf16(af1, bf1, acc[1][1], 0, 0, 0);
    }

    const int rq = (lane >> 4) * 4;
    #pragma unroll
    for (int fm = 0; fm < 2; ++fm) {
        #pragma unroll
        for (int fn = 0; fn < 2; ++fn) {
            const int col = bn + wn * 32 + fn * 16 + fr;
            const float bv = bias[col];
            #pragma unroll
            for (int j = 0; j < 4; ++j) {
                const int row = wm * 32 + fm * 16 + rq + j;
                p_batch[(size_t)row * D_ + col] = selu_f(acc[fm][fn][j] + bv);
            }
        }
    }
}

// Kernel D (fused): partial GEMV tiles; last block reduces -> hn -> p_stars,
// and computes r_stars. grid (NCG, NKG), block 256. Deterministic: partials at
// fixed slots; fixed-order reduction in the single winner block.
__global__ __launch_bounds__(256) void k_prod_fused(
        const float* __restrict__ p_batch,  // [64,532]
        const float* __restrict__ w_prod,   // [532,532]
        const float* __restrict__ b_prod,   // [532]
        const float* __restrict__ w_pff,    // [532,9]
        const float* __restrict__ b_pff,    // [9]
        const float* __restrict__ w_rff,    // [532]
        const float* __restrict__ b_rff,    // [1]
        float* __restrict__ part,           // ws [NKG][532]
        int* __restrict__ dcount,           // ws counter (=0 from kernel A)
        float* __restrict__ out_p,          // p_stars [9]
        float* __restrict__ out_r)          // r_stars [64]
{
    __shared__ float pbar[PCHUNK];
    __shared__ float red[2][PCHUNK];
    const int cg = blockIdx.x, kg = blockIdx.y;
    const int tid = threadIdx.x;
    const int cl = tid & (PCHUNK - 1);
    const int h  = tid >> 7;
    const int k0 = kg * PCHUNK;
    const int klen = min(PCHUNK, D_ - k0);

    if (cl < klen) {
        float s = 0.f;
        #pragma unroll 8
        for (int r = h * 32; r < h * 32 + 32; ++r)
            s += p_batch[(size_t)r * D_ + k0 + cl];
        red[h][cl] = s;
    }
    __syncthreads();
    if (h == 0 && cl < klen) pbar[cl] = (red[0][cl] + red[1][cl]) * (1.0f / 64.0f);
    __syncthreads();

    const int c = cg * PCHUNK + cl;
    float acc = 0.f;
    if (c < D_) {
        const int jb = h * 64;
        const int je = min(jb + 64, klen);
        for (int j = jb; j < je; ++j)
            acc = fmaf(pbar[j], w_prod[(size_t)(k0 + j) * D_ + c], acc);
    }
    red[h][cl] = acc;
    __syncthreads();
    if (h == 0 && c < D_) part[kg * D_ + c] = red[0][cl] + red[1][cl];

    // ---- last-block finalize ----
    __threadfence();                       // make partials device-visible
    __shared__ int is_last;
    if (tid == 0) is_last = (atomicAdd(dcount, 1) == NCG * NKG - 1);
    __syncthreads();
    if (!is_last) return;
    __threadfence();                       // acquire: see all partials

    __shared__ float hn[D_];
    __shared__ float rred[4][64];
    for (int cc = tid; cc < D_; cc += 256) {
        float s = b_prod[cc];
        #pragma unroll
        for (int g = 0; g < NKG; ++g) s += part[g * D_ + cc];
        hn[cc] = selu_f(s);
    }
    __syncthreads();
    if (tid < L_) {
        float a = 0.f;
        for (int k = 0; k < D_; ++k) a = fmaf(hn[k], w_pff[k * L_ + tid], a);
        out_p[tid] = selu_f(a + b_pff[tid]);
    }
    // r_stars: 4 k-quarters x 64 reviews (4*133 = 532)
    {
        const int r = tid & 63, q = tid >> 6;
        float pr = 0.f;
        for (int k = q * 133; k < (q + 1) * 133; ++k)
            pr = fmaf(p_batch[(size_t)r * D_ + k], w_rff[k], pr);
        rred[q][r] = pr;
    }
    __syncthreads();
    if (tid < 64)
        out_r[tid] = selu_f(rred[0][tid] + rred[1][tid] + rred[2][tid] + rred[3][tid]
                            + b_rff[0]);
}

extern "C" void kernel_launch(void* const* d_in, const int* in_sizes, int n_in,
                              void* d_out, int out_size, void* d_ws, size_t ws_size,
                              hipStream_t stream) {
    const int*   inputs     = (const int*)  d_in[0];
    const float* user_feats = (const float*)d_in[1];
    const float* emb        = (const float*)d_in[2];
    const float* w_sent     = (const float*)d_in[3];
    const float* b_sent     = (const float*)d_in[4];
    const float* w_rev      = (const float*)d_in[5];
    const float* b_rev      = (const float*)d_in[6];
    const float* w_prod     = (const float*)d_in[7];
    const float* b_prod     = (const float*)d_in[8];
    const float* w_rff      = (const float*)d_in[9];
    const float* b_rff      = (const float*)d_in[10];
    const float* w_pff      = (const float*)d_in[11];
    const float* b_pff      = (const float*)d_in[12];
    const float* user_w     = (const float*)d_in[13];
    float* out = (float*)d_out;   // [0..8] p_stars, [9..72] r_stars

    // workspace layout (float units, all 16B-aligned)
    float* ws = (float*)d_ws;
    __hip_bfloat16* sent_bf = (__hip_bfloat16*)(ws);            // 2048*512 bf16 = 524288 f
    __hip_bfloat16* wT      = (__hip_bfloat16*)(ws + 524288);   // 2*512*512 bf16 = 262144 f
    __hip_bfloat16* mrev    = (__hip_bfloat16*)(ws + 786432);   // 64*512 bf16 = 16384 f
    float* smask   = ws + 802816;    // 2048
    float* p_batch = ws + 804864;    // 64*532
    float* part    = ws + 838912;    // NKG*532
    int*   dcount  = (int*)(ws + 841600);

    k_fused_A<<<NSENT + 512, 256, 0, stream>>>(inputs, emb, w_sent, w_rev,
                                               sent_bf, wT, smask, dcount);
    k_gemm_sent_mean<<<dim3(E_ / 64, NSENT / 64), 256, 0, stream>>>(
        sent_bf, wT, b_sent, smask, mrev);
    k_gemm_rev<<<dim3(E_ / 64, 1), 256, 0, stream>>>(
        mrev, wT + (size_t)E_ * E_, b_rev, user_feats, user_w, p_batch);
    k_prod_fused<<<dim3(NCG, NKG), 256, 0, stream>>>(
        p_batch, w_prod, b_prod, w_pff, b_pff, w_rff, b_rff,
        part, dcount, out, out + L_);
}